// Round 6
// baseline (1023.010 us; speedup 1.0000x reference)
//
#include <hip/hip_runtime.h>
#include <hip/hip_bf16.h>
#include <cstdint>
#include <cstddef>

#define B_   8192
#define DX_  512
#define DZ_  1024
#define DY_  256
#define T_   4
#define NN_  6

typedef float f32x4 __attribute__((ext_vector_type(4)));
typedef short s16x8 __attribute__((ext_vector_type(8)));
typedef __hip_bfloat16 bf16;

__device__ __forceinline__ void gload_lds16(const bf16* g, void* l) {
  __builtin_amdgcn_global_load_lds(
      (const __attribute__((address_space(1))) void*)g,
      (__attribute__((address_space(3))) void*)l,
      16, 0, 0);
}

__device__ __forceinline__ float bf2f(unsigned short u) {
  union { unsigned int i; float f; } cv; cv.i = ((unsigned int)u) << 16; return cv.f;
}

__global__ void cvt_bf16_kernel(const float* __restrict__ in, bf16* __restrict__ out, int n4) {
  int i = blockIdx.x * blockDim.x + threadIdx.x;
  if (i >= n4) return;
  float4 v = ((const float4*)in)[i];
  ushort4 o;
  bf16 a0 = __float2bfloat16(v.x); o.x = *(unsigned short*)&a0;
  bf16 a1 = __float2bfloat16(v.y); o.y = *(unsigned short*)&a1;
  bf16 a2 = __float2bfloat16(v.z); o.z = *(unsigned short*)&a2;
  bf16 a3 = __float2bfloat16(v.w); o.w = *(unsigned short*)&a3;
  ((ushort4*)out)[i] = o;
}

__global__ void pack_bias_kernel(const float* __restrict__ a, const float* __restrict__ b,
                                 float* __restrict__ o) {
  int i = threadIdx.x;             // 512 threads
  o[i] = (i < DY_) ? a[i] : b[i - DY_];
}

// C[m,n] = act( preload + sum_k A[m,k]*W[n,k] ), preload = bias[n] (+ add1[m,n] unless MODE1).
// MODE: 0 = bf16 out; 1 = bf16 out_pre (pre-add1) + bf16 out (post-add1); 2 = fp32 split head.
// Block tile 128x128, 256 threads (4 waves 2x2, wave-tile 64x64), BK=32, 3-buffer LDS
// rotation (48KB -> 2 independent blocks/CU), depth-2 prefetch with counted vmcnt, one
// raw s_barrier per phase, reg frag double-buffer (unroll-by-2, named sets).
// Chunk-XOR swizzle: linear gload_lds dest + permuted global source + same XOR on read
// (verified 0 bank conflicts r2-r5).
template<int ACT, int MODE, bool HASADD>   // ACT: 0 none, 1 tanh, 2 sigmoid
__global__ __launch_bounds__(256, 2)
void gemm_bt(const bf16* __restrict__ A, int lda,
             const bf16* __restrict__ W, int ldw,
             const float* __restrict__ bias,
             const bf16* __restrict__ add1,
             bf16* __restrict__ out_pre,
             void* __restrict__ out, void* __restrict__ out2,
             int N, int K)
{
  __shared__ __align__(16) char ldsc[3 * 16384];   // [buf][A 8KB | B 8KB]
  const int t    = threadIdx.x;
  const int lane = t & 63;
  const int wave = t >> 6;
  const int m0 = blockIdx.x * 128;
  const int n0 = blockIdx.y * 128;

  // ---- staging: per tile, thread t stages 2 A-units + 2 B-units (16B each).
  // LDS unit u (per 4KB issue): row = u>>2 (0..63), pos = u&3; global chunk q = pos ^ ((row>>1)&3)
  const int rowA = t >> 2;                     // 0..63 (+64 on second issue)
  const int q    = (t & 3) ^ ((t >> 3) & 3);
  const bf16* gA  = A + (size_t)(m0 + rowA) * lda + q * 8;
  const bf16* gA2 = gA + (size_t)64 * lda;     // rows 64..127 (64>>1 ≡ 0 mod 4: same q)
  const bf16* gB  = W + (size_t)(n0 + rowA) * ldw + q * 8;
  const bf16* gB2 = gB + (size_t)64 * ldw;
  const int wb = wave * 1024;                  // wave-uniform LDS dest base (4 waves x 1KB = 4KB)

  auto stage = [&](int ko, int buf) {
    char* base = ldsc + buf * 16384;
    gload_lds16(gA  + ko, base + wb);
    gload_lds16(gA2 + ko, base + 4096 + wb);
    gload_lds16(gB  + ko, base + 8192 + wb);
    gload_lds16(gB2 + ko, base + 12288 + wb);
  };

  // ---- fragment addressing: 2x2 wave grid, wave-tile 64x64
  const int mo = (wave >> 1) * 64;
  const int no = (wave & 1) * 64;
  const int fr = lane & 15;                    // fragment row (A) / col (B)
  const int g4 = lane >> 4;                    // k sub-chunk 0..3
  const int rb = g4 * 4;                       // C/D row base
  const int kx = (g4 ^ ((fr >> 1) & 3)) * 16;  // swizzled chunk byte offset

  const int NT = K >> 5;                       // 8/16/32 here — even, >= 8

  // ---- prologue: stage tiles 0..2 first, then bias/addend loads
  stage(0, 0);
  stage(32, 1);
  stage(64, 2);
  __builtin_amdgcn_sched_barrier(0);

  float bv[4] = {0.f, 0.f, 0.f, 0.f};
  if (bias) {
#pragma unroll
    for (int j = 0; j < 4; ++j) bv[j] = bias[n0 + no + j * 16 + fr];
  }
  unsigned short adr[4][4][4];
  if (HASADD) {
#pragma unroll
    for (int f = 0; f < 4; ++f)
#pragma unroll
      for (int j = 0; j < 4; ++j) {
        const unsigned short* p = (const unsigned short*)add1
            + (size_t)(m0 + mo + f * 16 + rb) * N + (n0 + no + j * 16 + fr);
#pragma unroll
        for (int r = 0; r < 4; ++r) adr[f][j][r] = p[(size_t)r * N];
      }
  }

  // ---- accumulator preload (bias + addend folded in; MODE1 keeps addend for epilogue)
  f32x4 acc[4][4];
#pragma unroll
  for (int f = 0; f < 4; ++f)
#pragma unroll
    for (int j = 0; j < 4; ++j)
#pragma unroll
      for (int r = 0; r < 4; ++r) {
        float v = bv[j];
        if (HASADD && MODE != 1) v += bf2f(adr[f][j][r]);
        acc[f][j][r] = v;
      }

  // ---- frag helpers (named reg sets; compile-time indices under unroll)
  s16x8 aA[4], bA[4], aB[4], bB[4];
  auto ldfrags = [&](int kt, s16x8* fa, s16x8* fb) {
    const char* pA = ldsc + (kt % 3) * 16384;
    const char* pB = pA + 8192;
#pragma unroll
    for (int f = 0; f < 4; ++f) fa[f] = *(const s16x8*)(pA + (mo + f * 16 + fr) * 64 + kx);
#pragma unroll
    for (int j = 0; j < 4; ++j) fb[j] = *(const s16x8*)(pB + (no + j * 16 + fr) * 64 + kx);
  };
  auto domfma = [&](const s16x8* fa, const s16x8* fb) {
    __builtin_amdgcn_s_setprio(1);
#pragma unroll
    for (int f = 0; f < 4; ++f)
#pragma unroll
      for (int j = 0; j < 4; ++j)
        acc[f][j] = __builtin_amdgcn_mfma_f32_16x16x32_bf16(fa[f], fb[j], acc[f][j], 0, 0, 0);
    __builtin_amdgcn_s_setprio(0);
  };

  // tile 0 ready (tiles 1,2 = 8 loads may remain outstanding)
  asm volatile("s_waitcnt vmcnt(8)" ::: "memory");
  __builtin_amdgcn_s_barrier();
  __builtin_amdgcn_sched_barrier(0);
  ldfrags(0, aA, bA);

  for (int kt = 0; kt < NT; kt += 2) {
    // phase A: tile kt+1 ready; stage kt+3; read frags kt+1; compute kt
    if (kt + 2 < NT) asm volatile("s_waitcnt vmcnt(4)" ::: "memory");
    else             asm volatile("s_waitcnt vmcnt(0)" ::: "memory");
    __builtin_amdgcn_s_barrier();
    __builtin_amdgcn_sched_barrier(0);
    if (kt + 3 < NT) stage((kt + 3) << 5, (kt + 3) % 3);
    ldfrags(kt + 1, aB, bB);
    domfma(aA, bA);
    // phase B: tile kt+2 ready; stage kt+4; read frags kt+2; compute kt+1
    if (kt + 2 < NT) {
      if (kt + 3 < NT) asm volatile("s_waitcnt vmcnt(4)" ::: "memory");
      else             asm volatile("s_waitcnt vmcnt(0)" ::: "memory");
      __builtin_amdgcn_s_barrier();
      __builtin_amdgcn_sched_barrier(0);
      if (kt + 4 < NT) stage((kt + 4) << 5, (kt + 4) % 3);
      ldfrags(kt + 2, aA, bA);
    }
    domfma(aB, bB);
  }

  // ---- epilogue.  C/D layout: col = lane&15, row = (lane>>4)*4 + reg
#pragma unroll
  for (int f = 0; f < 4; ++f) {
#pragma unroll
    for (int j = 0; j < 4; ++j) {
      const int n = n0 + no + j * 16 + fr;
#pragma unroll
      for (int r = 0; r < 4; ++r) {
        const int m = m0 + mo + f * 16 + rb + r;
        float v = acc[f][j][r];
        if (MODE == 1) {
          out_pre[(size_t)m * N + n] = __float2bfloat16(v);
          v += bf2f(adr[f][j][r]);
        }
        if (ACT == 1)      { float e = __expf(2.f * v); v = 1.f - 2.f / (e + 1.f); }
        else if (ACT == 2) v = 1.f / (1.f + __expf(-v));
        if (MODE == 2) {
          if (n < DY_) ((float*)out)[(size_t)m * DY_ + n] = v;
          else         ((float*)out2)[(size_t)m * DY_ + (n - DY_)] = v;
        } else {
          ((bf16*)out)[(size_t)m * N + n] = __float2bfloat16(v);
        }
      }
    }
  }
}

extern "C" void kernel_launch(void* const* d_in, const int* in_sizes, int n_in,
                              void* d_out, int out_size, void* d_ws, size_t ws_size,
                              hipStream_t stream) {
  const float* xs  = (const float*)d_in[0];
  const float* Wx  = (const float*)d_in[1];
  const float* bx  = (const float*)d_in[2];
  const float* Wy  = (const float*)d_in[3];
  const float* by  = (const float*)d_in[4];
  const float* Wn  = (const float*)d_in[5];
  const float* bn  = (const float*)d_in[6];
  const float* Wu  = (const float*)d_in[7];
  const float* bu  = (const float*)d_in[8];
  const float* Wq  = (const float*)d_in[9];
  const float* bq  = (const float*)d_in[10];
  const float* ys0 = (const float*)d_in[11];
  const float* zs0 = (const float*)d_in[12];

  char* ws = (char*)d_ws;
  size_t off = 0;
  auto take = [&](size_t bytes) -> char* {
    char* p = ws + off;
    off += (bytes + 255) & ~(size_t)255;
    return p;
  };

  bf16*  Wn_b  = (bf16*)take((size_t)DZ_ * 3 * DZ_ * 2);
  bf16*  Wx_b  = (bf16*)take((size_t)DZ_ * DX_ * 2);
  bf16*  Wy_b  = (bf16*)take((size_t)DZ_ * DY_ * 2);
  bf16*  Wuq_b = (bf16*)take((size_t)2 * DY_ * DZ_ * 2);
  float* buq   = (float*)take((size_t)2 * DY_ * 4);
  bf16*  ys_b  = (bf16*)take((size_t)B_ * DZ_ * 2);
  bf16*  z_a   = (bf16*)take((size_t)B_ * DZ_ * 2);
  bf16*  z_b   = (bf16*)take((size_t)B_ * DZ_ * 2);
  bf16*  cx    = (bf16*)take((size_t)B_ * DZ_ * 2);
  bf16*  cy    = (bf16*)take((size_t)B_ * DZ_ * 2);
  bf16*  c     = (bf16*)take((size_t)B_ * DZ_ * 2);
  // aliases into regions not yet live at time of use:
  bf16* xs_b   = c;                                   // dead before c first written
  bf16* ysin_b = (bf16*)((char*)c + (size_t)B_ * DX_ * 2);  // 8.4+4.2 MB <= 16.7 MB
  bf16* xse_b  = cy;                                  // dead before cy first written

  auto cvt = [&](const float* src, bf16* dst, size_t n) {
    int n4 = (int)(n / 4);
    cvt_bf16_kernel<<<(n4 + 255) / 256, 256, 0, stream>>>(src, dst, n4);
  };
  cvt(Wn, Wn_b, (size_t)DZ_ * 3 * DZ_);
  cvt(Wx, Wx_b, (size_t)DZ_ * DX_);
  cvt(Wy, Wy_b, (size_t)DZ_ * DY_);
  cvt(Wu, Wuq_b, (size_t)DY_ * DZ_);
  cvt(Wq, Wuq_b + (size_t)DY_ * DZ_, (size_t)DY_ * DZ_);
  cvt(xs, xs_b, (size_t)B_ * DX_);
  cvt(ys0, ysin_b, (size_t)B_ * DY_);
  cvt(zs0, z_a, (size_t)B_ * DZ_);
  pack_bias_kernel<<<1, 512, 0, stream>>>(bu, bq, buq);

  const dim3 blk(256);
  const dim3 gz(B_ / 128, DZ_ / 128);   // 64 x 8 = 512 blocks (2/CU)
  const dim3 gh(B_ / 128, 4);           // head: N=512 -> 64 x 4

  // xs_e = xs@Wx.T + bx  (bf16)
  gemm_bt<0, 0, false><<<gz, blk, 0, stream>>>(xs_b, DX_, Wx_b, DX_, bx, nullptr, nullptr, xse_b, nullptr, DZ_, DX_);
  // ys_e = ys0@Wy.T + by (bf16)
  gemm_bt<0, 0, false><<<gz, blk, 0, stream>>>(ysin_b, DY_, Wy_b, DY_, by, nullptr, nullptr, ys_b, nullptr, DZ_, DY_);
  // cx = xs_e@Wnx.T (bf16)
  gemm_bt<0, 0, false><<<gz, blk, 0, stream>>>(xse_b, DZ_, Wn_b, 3 * DZ_, nullptr, nullptr, nullptr, cx, nullptr, DZ_, DZ_);

  bf16* zc = z_a;
  bf16* zn = z_b;
  for (int tt = 0; tt < T_; ++tt) {
    // cy = ys_e@Wny.T + bn ; c = cy + cx  (both bf16, one GEMM)
    gemm_bt<0, 1, true><<<gz, blk, 0, stream>>>(ys_b, DZ_, Wn_b + DZ_, 3 * DZ_, bn, cx, cy, c, nullptr, DZ_, DZ_);
    for (int i = 0; i < NN_; ++i) {
      // z = tanh(c + z@Wnz.T)   (addend preloaded into acc)
      gemm_bt<1, 0, true><<<gz, blk, 0, stream>>>(zc, DZ_, Wn_b + 2 * DZ_, 3 * DZ_, nullptr, c, nullptr, zn, nullptr, DZ_, DZ_);
      bf16* tmp = zc; zc = zn; zn = tmp;
    }
    // ys_e = tanh(cy + z@Wnz.T)
    gemm_bt<1, 0, true><<<gz, blk, 0, stream>>>(zc, DZ_, Wn_b + 2 * DZ_, 3 * DZ_, nullptr, cy, nullptr, ys_b, nullptr, DZ_, DZ_);
  }

  float* outp = (float*)d_out;
  // y_hat | q_hat = sigmoid(ys_e@[Wu;Wq].T + [bu;bq]) — one N=512 GEMM, split store
  gemm_bt<2, 2, false><<<gh, blk, 0, stream>>>(ys_b, DZ_, Wuq_b, DZ_, buq, nullptr, nullptr,
                                               outp, outp + (size_t)B_ * DY_, 2 * DY_, DZ_);
}

// Round 7
// 941.838 us; speedup vs baseline: 1.0862x; 1.0862x over previous
//
#include <hip/hip_runtime.h>
#include <hip/hip_bf16.h>
#include <cstdint>
#include <cstddef>

#define B_   8192
#define DX_  512
#define DZ_  1024
#define DY_  256
#define T_   4
#define NN_  6

typedef float f32x4 __attribute__((ext_vector_type(4)));
typedef short s16x8 __attribute__((ext_vector_type(8)));
typedef __hip_bfloat16 bf16;

__device__ __forceinline__ void gload_lds16(const bf16* g, void* l) {
  __builtin_amdgcn_global_load_lds(
      (const __attribute__((address_space(1))) void*)g,
      (__attribute__((address_space(3))) void*)l,
      16, 0, 0);
}

__device__ __forceinline__ float bf2f(unsigned short u) {
  union { unsigned int i; float f; } cv; cv.i = ((unsigned int)u) << 16; return cv.f;
}

__global__ void cvt_bf16_kernel(const float* __restrict__ in, bf16* __restrict__ out, int n4) {
  int i = blockIdx.x * blockDim.x + threadIdx.x;
  if (i >= n4) return;
  float4 v = ((const float4*)in)[i];
  ushort4 o;
  bf16 a0 = __float2bfloat16(v.x); o.x = *(unsigned short*)&a0;
  bf16 a1 = __float2bfloat16(v.y); o.y = *(unsigned short*)&a1;
  bf16 a2 = __float2bfloat16(v.z); o.z = *(unsigned short*)&a2;
  bf16 a3 = __float2bfloat16(v.w); o.w = *(unsigned short*)&a3;
  ((ushort4*)out)[i] = o;
}

__global__ void pack_bias_kernel(const float* __restrict__ a, const float* __restrict__ b,
                                 float* __restrict__ o) {
  int i = threadIdx.x;             // 512 threads
  o[i] = (i < DY_) ? a[i] : b[i - DY_];
}

// C[m,n] = act( preload + sum_k A[m,k]*W[n,k] ), preload = bias[n] (+ add1[m,n] if HASADD
// and MODE!=1; MODE1 re-reads add1 in the epilogue and also stores the pre-add value).
// MODE: 0 = bf16 out; 1 = bf16 out_pre (pre-add1) + bf16 out (post-add1); 2 = fp32 split head.
// m201-style fine-interleaved schedule: BM=256 x BN=128, 512 threads (8 waves 4Mx2N,
// wave-tile 64x64), K-tile 64, THREE 48KB LDS buffers (144KB, 1 block/CU), stage
// distance 2 K-tiles, counted vmcnt(6) (never 0 mid-loop). Per K-tile two phases:
// {ds_read 8xb128 -> s_barrier -> lgkmcnt(0) -> setprio(1) -> 16 MFMA -> setprio(0)},
// stages + vmcnt in phase B. Buffer reuse safety: overwrite is issued >= 2 barriers
// after the last read, and readers pass lgkmcnt(0) before the intervening barrier.
// Chunk-XOR swizzle (8 chunks/128B row): linear gload_lds dest + permuted global
// source q = pos ^ (row&7) + same XOR on read (0 bank conflicts measured r2-r6).
template<int ACT, int MODE, bool HASADD>   // ACT: 0 none, 1 tanh, 2 sigmoid
__global__ __launch_bounds__(512, 2)
void gemm_bt(const bf16* __restrict__ A, int lda,
             const bf16* __restrict__ W, int ldw,
             const float* __restrict__ bias,
             const bf16* __restrict__ add1,
             bf16* __restrict__ out_pre,
             void* __restrict__ out, void* __restrict__ out2,
             int N, int K)
{
  __shared__ __align__(16) char ldsc[3 * 49152];   // [buf][A 32KB | B 16KB]
  const int t    = threadIdx.x;
  const int lane = t & 63;
  const int wave = t >> 6;
  const int m0 = blockIdx.x * 256;
  const int n0 = blockIdx.y * 128;

  // ---- staging: unit u = i*512 + t per gload; row = u>>3, pos = u&7 (16B chunks,
  // 8 per 128B row). Source-permuted chunk q = pos ^ (row&7); i*64 ≡ 0 mod 8 so q
  // is i-invariant.
  const int srow = t >> 3;                     // 0..63 (+64*i per gload)
  const int q    = (t & 7) ^ ((t >> 3) & 7);
  const bf16* gA = A + (size_t)(m0 + srow) * lda + q * 8;
  const bf16* gB = W + (size_t)(n0 + srow) * ldw + q * 8;
  const int wb = wave * 1024;                  // wave-uniform LDS dest base

  auto stage = [&](int kt) {                   // 6 gloads: A 4x8KB, B 2x8KB
    char* base = ldsc + (kt % 3) * 49152;
    const int ko = kt << 6;
#pragma unroll
    for (int i = 0; i < 4; ++i)
      gload_lds16(gA + (size_t)(i * 64) * lda + ko, base + i * 8192 + wb);
#pragma unroll
    for (int i = 0; i < 2; ++i)
      gload_lds16(gB + (size_t)(i * 64) * ldw + ko, base + 32768 + i * 8192 + wb);
  };

  // ---- fragment addressing: wave grid 4Mx2N, wave-tile 64x64 (4x4 frags 16x16x32)
  const int mo = (wave >> 1) * 64;
  const int no = (wave & 1) * 64;
  const int fr = lane & 15;                    // fragment row (A) / col (B)
  const int g4 = lane >> 4;                    // k sub-chunk 0..3
  const int rb = g4 * 4;                       // C/D row base

  const int NT = K >> 6;                       // K-tiles of 64: 4/8/16 here

  // ---- prologue loads: bias + addend first (drained by acc init), then tiles 0,1.
  float bv[4] = {0.f, 0.f, 0.f, 0.f};
  if (bias) {
#pragma unroll
    for (int j = 0; j < 4; ++j) bv[j] = bias[n0 + no + j * 16 + fr];
  }
  unsigned short adr[4][4][4];
  if (HASADD && MODE != 1) {
#pragma unroll
    for (int f = 0; f < 4; ++f)
#pragma unroll
      for (int j = 0; j < 4; ++j) {
        const unsigned short* p = (const unsigned short*)add1
            + (size_t)(m0 + mo + f * 16 + rb) * N + (n0 + no + j * 16 + fr);
#pragma unroll
        for (int r = 0; r < 4; ++r) adr[f][j][r] = p[(size_t)r * N];
      }
  }
  __builtin_amdgcn_sched_barrier(0);
  stage(0);
  stage(1);
  __builtin_amdgcn_sched_barrier(0);

  // ---- accumulator preload (compiler's waitcnt for adr drains addend loads only)
  f32x4 acc[4][4];
#pragma unroll
  for (int f = 0; f < 4; ++f)
#pragma unroll
    for (int j = 0; j < 4; ++j)
#pragma unroll
      for (int r = 0; r < 4; ++r) {
        float v = bv[j];
        if (HASADD && MODE != 1) v += bf2f(adr[f][j][r]);
        acc[f][j][r] = v;
      }

  // ---- frag helpers (named reg sets; compile-time indices under unroll)
  s16x8 a0[4], b0[4], a1[4], b1[4];
  auto ldfrags = [&](int kt, int s, s16x8* fa, s16x8* fb) {
    const char* pA = ldsc + (kt % 3) * 49152;
    const char* pB = pA + 32768;
    const int cb = ((s * 4 + g4) ^ (fr & 7)) * 16;   // swizzled chunk byte offset
#pragma unroll
    for (int f = 0; f < 4; ++f) fa[f] = *(const s16x8*)(pA + (mo + f * 16 + fr) * 128 + cb);
#pragma unroll
    for (int j = 0; j < 4; ++j) fb[j] = *(const s16x8*)(pB + (no + j * 16 + fr) * 128 + cb);
  };
  auto domfma = [&](const s16x8* fa, const s16x8* fb) {
    __builtin_amdgcn_s_setprio(1);
#pragma unroll
    for (int f = 0; f < 4; ++f)
#pragma unroll
      for (int j = 0; j < 4; ++j)
        acc[f][j] = __builtin_amdgcn_mfma_f32_16x16x32_bf16(fa[f], fb[j], acc[f][j], 0, 0, 0);
    __builtin_amdgcn_s_setprio(0);
  };

  // tile 0 resident (tile 1's 6 loads may stay in flight)
  asm volatile("s_waitcnt vmcnt(6)" ::: "memory");
  __builtin_amdgcn_s_barrier();

  for (int kt = 0; kt < NT; ++kt) {
    // phase A: read k-half 0 of tile kt; compute
    ldfrags(kt, 0, a0, b0);
    __builtin_amdgcn_sched_barrier(0);
    __builtin_amdgcn_s_barrier();
    asm volatile("s_waitcnt lgkmcnt(0)" ::: "memory");
    __builtin_amdgcn_sched_barrier(0);
    domfma(a0, b0);
    // phase B: read k-half 1; stage tile kt+2; counted vmcnt (tile kt+1 resident)
    ldfrags(kt, 1, a1, b1);
    if (kt + 2 < NT) stage(kt + 2);
    __builtin_amdgcn_sched_barrier(0);
    if (kt + 2 < NT) asm volatile("s_waitcnt vmcnt(6)" ::: "memory");
    else             asm volatile("s_waitcnt vmcnt(0)" ::: "memory");
    __builtin_amdgcn_s_barrier();
    asm volatile("s_waitcnt lgkmcnt(0)" ::: "memory");
    __builtin_amdgcn_sched_barrier(0);
    domfma(a1, b1);
  }

  // ---- epilogue.  C/D layout: col = lane&15, row = (lane>>4)*4 + reg
#pragma unroll
  for (int f = 0; f < 4; ++f) {
#pragma unroll
    for (int j = 0; j < 4; ++j) {
      const int n = n0 + no + j * 16 + fr;
#pragma unroll
      for (int r = 0; r < 4; ++r) {
        const int m = m0 + mo + f * 16 + rb + r;
        float v = acc[f][j][r];
        if (MODE == 1) {
          out_pre[(size_t)m * N + n] = __float2bfloat16(v);
          v += bf2f(((const unsigned short*)add1)[(size_t)m * N + n]);
        }
        if (ACT == 1)      { float e = __expf(2.f * v); v = 1.f - 2.f / (e + 1.f); }
        else if (ACT == 2) v = 1.f / (1.f + __expf(-v));
        if (MODE == 2) {
          if (n < DY_) ((float*)out)[(size_t)m * DY_ + n] = v;
          else         ((float*)out2)[(size_t)m * DY_ + (n - DY_)] = v;
        } else {
          ((bf16*)out)[(size_t)m * N + n] = __float2bfloat16(v);
        }
      }
    }
  }
}

extern "C" void kernel_launch(void* const* d_in, const int* in_sizes, int n_in,
                              void* d_out, int out_size, void* d_ws, size_t ws_size,
                              hipStream_t stream) {
  const float* xs  = (const float*)d_in[0];
  const float* Wx  = (const float*)d_in[1];
  const float* bx  = (const float*)d_in[2];
  const float* Wy  = (const float*)d_in[3];
  const float* by  = (const float*)d_in[4];
  const float* Wn  = (const float*)d_in[5];
  const float* bn  = (const float*)d_in[6];
  const float* Wu  = (const float*)d_in[7];
  const float* bu  = (const float*)d_in[8];
  const float* Wq  = (const float*)d_in[9];
  const float* bq  = (const float*)d_in[10];
  const float* ys0 = (const float*)d_in[11];
  const float* zs0 = (const float*)d_in[12];

  char* ws = (char*)d_ws;
  size_t off = 0;
  auto take = [&](size_t bytes) -> char* {
    char* p = ws + off;
    off += (bytes + 255) & ~(size_t)255;
    return p;
  };

  bf16*  Wn_b  = (bf16*)take((size_t)DZ_ * 3 * DZ_ * 2);
  bf16*  Wx_b  = (bf16*)take((size_t)DZ_ * DX_ * 2);
  bf16*  Wy_b  = (bf16*)take((size_t)DZ_ * DY_ * 2);
  bf16*  Wuq_b = (bf16*)take((size_t)2 * DY_ * DZ_ * 2);
  float* buq   = (float*)take((size_t)2 * DY_ * 4);
  bf16*  ys_b  = (bf16*)take((size_t)B_ * DZ_ * 2);
  bf16*  z_a   = (bf16*)take((size_t)B_ * DZ_ * 2);
  bf16*  z_b   = (bf16*)take((size_t)B_ * DZ_ * 2);
  bf16*  cx    = (bf16*)take((size_t)B_ * DZ_ * 2);
  bf16*  cy    = (bf16*)take((size_t)B_ * DZ_ * 2);
  bf16*  c     = (bf16*)take((size_t)B_ * DZ_ * 2);
  // aliases into regions not yet live at time of use:
  bf16* xs_b   = c;                                   // dead before c first written
  bf16* ysin_b = (bf16*)((char*)c + (size_t)B_ * DX_ * 2);  // 8.4+4.2 MB <= 16.7 MB
  bf16* xse_b  = cy;                                  // dead before cy first written

  auto cvt = [&](const float* src, bf16* dst, size_t n) {
    int n4 = (int)(n / 4);
    cvt_bf16_kernel<<<(n4 + 255) / 256, 256, 0, stream>>>(src, dst, n4);
  };
  cvt(Wn, Wn_b, (size_t)DZ_ * 3 * DZ_);
  cvt(Wx, Wx_b, (size_t)DZ_ * DX_);
  cvt(Wy, Wy_b, (size_t)DZ_ * DY_);
  cvt(Wu, Wuq_b, (size_t)DY_ * DZ_);
  cvt(Wq, Wuq_b + (size_t)DY_ * DZ_, (size_t)DY_ * DZ_);
  cvt(xs, xs_b, (size_t)B_ * DX_);
  cvt(ys0, ysin_b, (size_t)B_ * DY_);
  cvt(zs0, z_a, (size_t)B_ * DZ_);
  pack_bias_kernel<<<1, 512, 0, stream>>>(bu, bq, buq);

  const dim3 blk(512);
  const dim3 gz(B_ / 256, DZ_ / 128);   // 32 x 8 = 256 blocks = 1/CU
  const dim3 gh(B_ / 256, 4);           // head: N=512 -> 32 x 4

  // xs_e = xs@Wx.T + bx  (bf16)
  gemm_bt<0, 0, false><<<gz, blk, 0, stream>>>(xs_b, DX_, Wx_b, DX_, bx, nullptr, nullptr, xse_b, nullptr, DZ_, DX_);
  // ys_e = ys0@Wy.T + by (bf16)
  gemm_bt<0, 0, false><<<gz, blk, 0, stream>>>(ysin_b, DY_, Wy_b, DY_, by, nullptr, nullptr, ys_b, nullptr, DZ_, DY_);
  // cx = xs_e@Wnx.T (bf16)
  gemm_bt<0, 0, false><<<gz, blk, 0, stream>>>(xse_b, DZ_, Wn_b, 3 * DZ_, nullptr, nullptr, nullptr, cx, nullptr, DZ_, DZ_);

  bf16* zc = z_a;
  bf16* zn = z_b;
  for (int tt = 0; tt < T_; ++tt) {
    // cy = ys_e@Wny.T + bn ; c = cy + cx  (both bf16, one GEMM)
    gemm_bt<0, 1, true><<<gz, blk, 0, stream>>>(ys_b, DZ_, Wn_b + DZ_, 3 * DZ_, bn, cx, cy, c, nullptr, DZ_, DZ_);
    for (int i = 0; i < NN_; ++i) {
      // z = tanh(c + z@Wnz.T)   (addend preloaded into acc)
      gemm_bt<1, 0, true><<<gz, blk, 0, stream>>>(zc, DZ_, Wn_b + 2 * DZ_, 3 * DZ_, nullptr, c, nullptr, zn, nullptr, DZ_, DZ_);
      bf16* tmp = zc; zc = zn; zn = tmp;
    }
    // ys_e = tanh(cy + z@Wnz.T)
    gemm_bt<1, 0, true><<<gz, blk, 0, stream>>>(zc, DZ_, Wn_b + 2 * DZ_, 3 * DZ_, nullptr, cy, nullptr, ys_b, nullptr, DZ_, DZ_);
  }

  float* outp = (float*)d_out;
  // y_hat | q_hat = sigmoid(ys_e@[Wu;Wq].T + [bu;bq]) — one N=512 GEMM, split store
  gemm_bt<2, 2, false><<<gh, blk, 0, stream>>>(ys_b, DZ_, Wuq_b, DZ_, buq, nullptr, nullptr,
                                               outp, outp + (size_t)B_ * DY_, 2 * DY_, DZ_);
}